// Round 5
// baseline (229.276 us; speedup 1.0000x reference)
//
#include <hip/hip_runtime.h>
#include <hip/hip_bf16.h>
#include <stdint.h>

typedef unsigned short u16;
typedef __attribute__((ext_vector_type(8))) short bf16x8;
typedef __attribute__((ext_vector_type(4))) float f32x4;

#define LDS_AS(p) ((__attribute__((address_space(3))) void*)(p))
#define GLB_AS(p) ((__attribute__((address_space(1))) void*)(p))

__device__ __forceinline__ u16 f2bf(float f) {
  union { float f; uint32_t u; } v; v.f = f;
  uint32_t u = v.u;
  u += 0x7fffu + ((u >> 16) & 1u);
  return (u16)(u >> 16);
}

// ---------------- fp32 -> bf16 conversion ----------------
__device__ __forceinline__ void cvt8(const float* __restrict__ s, u16* __restrict__ d) {
  const float4* sv = (const float4*)s;
  float4 a = sv[0], b = sv[1];
  uint4 o;
  o.x = (uint32_t)f2bf(a.x) | ((uint32_t)f2bf(a.y) << 16);
  o.y = (uint32_t)f2bf(a.z) | ((uint32_t)f2bf(a.w) << 16);
  o.z = (uint32_t)f2bf(b.x) | ((uint32_t)f2bf(b.y) << 16);
  o.w = (uint32_t)f2bf(b.z) | ((uint32_t)f2bf(b.w) << 16);
  *(uint4*)d = o;
}

__global__ __launch_bounds__(256) void k_convert(
    const float* __restrict__ x, const float* __restrict__ wq, const float* __restrict__ wp,
    u16* __restrict__ xb, u16* __restrict__ wqb, u16* __restrict__ wpb) {
  int tid = blockIdx.x * 256 + threadIdx.x;
  int np  = gridDim.x * 256;
  for (int i = tid; i < (8192*768)/8; i += np) cvt8(x  + (size_t)i*8, xb  + (size_t)i*8);
  for (int i = tid; i < (2304*768)/8; i += np) cvt8(wq + (size_t)i*8, wqb + (size_t)i*8);
  for (int i = tid; i < (768*768)/8;  i += np) cvt8(wp + (size_t)i*8, wpb + (size_t)i*8);
}

// ---------------- shared 128x128 bf16 GEMM mainloop (A[M,768] . B[N,768]^T) ----------------
__device__ __forceinline__ void gemm_core(const u16* __restrict__ A,
                                          const u16* __restrict__ B,
                                          u16* As, u16* Bs,
                                          int rowA0, int rowB0,
                                          f32x4 acc[4][4]) {
  const int t  = threadIdx.x;
  const int lane = t & 63;
  const int wv = t >> 6;
  const int wr = wv >> 1, wc = wv & 1;
  const int lr = lane & 15, lg = lane >> 4;

#pragma unroll 1
  for (int kt = 0; kt < 24; ++kt) {
    const int k0 = kt * 32;
    __syncthreads();
#pragma unroll
    for (int p = 0; p < 2; ++p) {
      int idx = p * 256 + t;
      int row = idx >> 2;
      int cc  = (idx & 3) ^ ((row >> 1) & 3);
      __builtin_amdgcn_global_load_lds(GLB_AS(A + (size_t)(rowA0 + row) * 768 + k0 + cc * 8),
                                       LDS_AS(As + idx * 8), 16, 0, 0);
    }
#pragma unroll
    for (int p = 0; p < 2; ++p) {
      int idx = p * 256 + t;
      int row = idx >> 2;
      int cc  = (idx & 3) ^ ((row >> 1) & 3);
      __builtin_amdgcn_global_load_lds(GLB_AS(B + (size_t)(rowB0 + row) * 768 + k0 + cc * 8),
                                       LDS_AS(Bs + idx * 8), 16, 0, 0);
    }
    asm volatile("s_waitcnt vmcnt(0)" ::: "memory");
    __syncthreads();

    bf16x8 af[4], bf_[4];
#pragma unroll
    for (int mi = 0; mi < 4; ++mi) {
      int row = wr * 64 + mi * 16 + lr;
      int cc  = lg ^ ((row >> 1) & 3);
      af[mi] = *(const bf16x8*)(As + row * 32 + cc * 8);
    }
#pragma unroll
    for (int ni = 0; ni < 4; ++ni) {
      int row = wc * 64 + ni * 16 + lr;
      int cc  = lg ^ ((row >> 1) & 3);
      bf_[ni] = *(const bf16x8*)(Bs + row * 32 + cc * 8);
    }
#pragma unroll
    for (int mi = 0; mi < 4; ++mi)
#pragma unroll
      for (int ni = 0; ni < 4; ++ni)
        acc[mi][ni] = __builtin_amdgcn_mfma_f32_16x16x32_bf16(af[mi], bf_[ni], acc[mi][ni], 0, 0, 0);
  }
}

// ---------------- GEMM1: qkv projection + scatter into Qhat/Khat/V ----------------
__global__ __launch_bounds__(256) void k_gemm_qkv(
    const u16* __restrict__ Aq, const u16* __restrict__ Bw, const float* __restrict__ bias,
    u16* __restrict__ Qh, u16* __restrict__ Kh, u16* __restrict__ Vp) {
  __shared__ u16 As[128 * 32];
  __shared__ u16 Bs[128 * 32];
  int bid = blockIdx.x;
  int wg  = (bid & 7) * 144 + (bid >> 3);
  int bx  = wg % 18, by = wg / 18;

  f32x4 acc[4][4];
#pragma unroll
  for (int mi = 0; mi < 4; ++mi)
#pragma unroll
    for (int ni = 0; ni < 4; ++ni) acc[mi][ni] = (f32x4){0.f, 0.f, 0.f, 0.f};

  gemm_core(Aq, Bw, As, Bs, by * 128, bx * 128, acc);

  const float gam = 0.7905694150420949f;
  const float sc1 = __builtin_sqrtf(0.09375f / gam);
  const float sc2 = __builtin_sqrtf(0.03125f / gam);

  const int t = threadIdx.x, lane = t & 63, wv = t >> 6;
  const int wr = wv >> 1, wc = wv & 1, lr = lane & 15, lg = lane >> 4;
  const int colBase = bx * 128 + wc * 64;
  const int tsec = (bx * 128) / 768;

  float bv[4];
#pragma unroll
  for (int ni = 0; ni < 4; ++ni) bv[ni] = bias[colBase + ni * 16 + lr];

#pragma unroll
  for (int mi = 0; mi < 4; ++mi) {
    int tok0 = by * 128 + wr * 64 + mi * 16 + lg * 4;
#pragma unroll
    for (int ni = 0; ni < 4; ++ni) {
      int colsec = colBase - tsec * 768 + ni * 16 + lr;
      int h = colsec >> 6, d = colsec & 63;
#pragma unroll
      for (int r = 0; r < 4; ++r) {
        int tok = tok0 + r;
        int b = tok >> 10, n = tok & 1023;
        float val = acc[mi][ni][r] + bv[ni];
        size_t rowq = (size_t)(b * 12 + h) * 1024 + n;
        if (tsec == 0) {
          Qh[rowq * 128 + d]      = f2bf(val * sc1);
          Kh[rowq * 128 + 64 + d] = f2bf(val * sc2);
        } else if (tsec == 1) {
          Qh[rowq * 128 + 64 + d] = f2bf(val * sc2);
          Kh[rowq * 128 + d]      = f2bf(val * sc1);
        } else {
          Vp[rowq * 64 + d] = f2bf(val);
        }
      }
    }
  }
}

// ---------------- V transpose: Vp[bh][n][d] -> Vt[bh][d][n] ----------------
__global__ __launch_bounds__(256) void k_transpose_v(const u16* __restrict__ Vp, u16* __restrict__ Vt) {
  __shared__ u16 tile[64 * 72];
  int bid = blockIdx.x;
  int bh = bid >> 4, nb = bid & 15;
  int t = threadIdx.x;
  {
    int r = t >> 2, c0 = (t & 3) * 16;
    const u16* src = Vp + ((size_t)bh * 1024 + nb * 64 + r) * 64 + c0;
    uint4 a = *(const uint4*)src;
    uint4 b = *(const uint4*)(src + 8);
    *(uint4*)(tile + r * 72 + c0)     = a;
    *(uint4*)(tile + r * 72 + c0 + 8) = b;
  }
  __syncthreads();
  {
    int d = t >> 2, n0 = (t & 3) * 16;
    union { uint4 v; u16 s[8]; } p0, p1;
#pragma unroll
    for (int j = 0; j < 8; ++j) p0.s[j] = tile[(n0 + j) * 72 + d];
#pragma unroll
    for (int j = 0; j < 8; ++j) p1.s[j] = tile[(n0 + 8 + j) * 72 + d];
    u16* dst = Vt + ((size_t)bh * 64 + d) * 1024 + nb * 64 + n0;
    *(uint4*)dst       = p0.v;
    *(uint4*)(dst + 8) = p1.v;
  }
}

// ---------------- fused flash attention: NO K/V staging (L2-resident), NO barriers ----------------
// S^T = Khat . Qhat^T ; p = exp(-10/(e^{0.4 s}+1)) ; O^T = V^T . P ; O /= sum_j p
// K/V MFMA fragments loaded directly from global (L2-served). Only per-wave P LDS round-trip.
__global__ __launch_bounds__(256, 3) void k_attn(
    const u16* __restrict__ Qh, const u16* __restrict__ Kh, const u16* __restrict__ Vt,
    u16* __restrict__ attn) {
  __shared__ u16 Ps[4][32 * 72];    // per-wave P [32 i][64 j], stride 72 u16 (rows 16B-aligned)

  int bid = blockIdx.x;
  int wg = (bid & 7) * 96 + (bid >> 3);   // 768 = 8*96; 8 qb-blocks of a head stay on one XCD
  int bh = wg >> 3, qb = wg & 7;          // 8 q-blocks of 128 rows
  int b = bh / 12, h = bh % 12;

  const int t = threadIdx.x, lane = t & 63, wv = t >> 6;
  const int lr = lane & 15, lg = lane >> 4;

  const u16* __restrict__ Kb = Kh + (size_t)bh * 1024 * 128;
  const u16* __restrict__ Vb = Vt + (size_t)bh * 64 * 1024;

  // Q fragments: qf[it][kk] = Qhat[token = qb*128 + wv*32 + it*16 + lr][k = kk*32 + lg*8 ..+8]
  bf16x8 qf[2][4];
  {
    const u16* qp = Qh + ((size_t)bh * 1024 + qb * 128 + wv * 32 + lr) * 128 + lg * 8;
#pragma unroll
    for (int it = 0; it < 2; ++it)
#pragma unroll
      for (int kk = 0; kk < 4; ++kk)
        qf[it][kk] = *(const bf16x8*)(qp + it * 16 * 128 + kk * 32);
  }

  f32x4 acc_o[4][2];
#pragma unroll
  for (int dt = 0; dt < 4; ++dt)
#pragma unroll
    for (int it = 0; it < 2; ++it) acc_o[dt][it] = (f32x4){0.f, 0.f, 0.f, 0.f};
  float dsum[2] = {0.f, 0.f};

  u16* pw = Ps[wv];

#pragma unroll 1
  for (int kt = 0; kt < 16; ++kt) {
    // ---- S^T tile: accs[jt][it]; A-frag = Khat row j = kt*64 + jt*16 + lr, k-feat = kk*32+lg*8 ----
    f32x4 accs[4][2];
#pragma unroll
    for (int jt = 0; jt < 4; ++jt)
#pragma unroll
      for (int it = 0; it < 2; ++it) accs[jt][it] = (f32x4){0.f, 0.f, 0.f, 0.f};
#pragma unroll
    for (int jt = 0; jt < 4; ++jt) {
      const u16* krow = Kb + (size_t)(kt * 64 + jt * 16 + lr) * 128 + lg * 8;
      bf16x8 kf[4];
#pragma unroll
      for (int kk = 0; kk < 4; ++kk) kf[kk] = *(const bf16x8*)(krow + kk * 32);
#pragma unroll
      for (int kk = 0; kk < 4; ++kk)
#pragma unroll
        for (int it = 0; it < 2; ++it)
          accs[jt][it] = __builtin_amdgcn_mfma_f32_16x16x32_bf16(kf[kk], qf[it][kk], accs[jt][it], 0, 0, 0);
    }

    // ---- p + packed P write: row i = it*16+lr, cols j = jt*16+lg*4..+3 ----
#pragma unroll
    for (int jt = 0; jt < 4; ++jt) {
#pragma unroll
      for (int it = 0; it < 2; ++it) {
        float p0 = __expf(-10.0f * __builtin_amdgcn_rcpf(__expf(0.4f * accs[jt][it][0]) + 1.0f));
        float p1 = __expf(-10.0f * __builtin_amdgcn_rcpf(__expf(0.4f * accs[jt][it][1]) + 1.0f));
        float p2 = __expf(-10.0f * __builtin_amdgcn_rcpf(__expf(0.4f * accs[jt][it][2]) + 1.0f));
        float p3 = __expf(-10.0f * __builtin_amdgcn_rcpf(__expf(0.4f * accs[jt][it][3]) + 1.0f));
        dsum[it] += (p0 + p1) + (p2 + p3);
        uint2 w;
        w.x = (uint32_t)f2bf(p0) | ((uint32_t)f2bf(p1) << 16);
        w.y = (uint32_t)f2bf(p2) | ((uint32_t)f2bf(p3) << 16);
        *(uint2*)(pw + (it * 16 + lr) * 72 + jt * 16 + lg * 4) = w;
      }
    }

    // forbid compiler from reordering the P reads above the P writes (differently-typed LDS access)
    asm volatile("" ::: "memory");

    // ---- O^T += mfma(V-frag, P-frag); V-frag direct from global: row d = dt*16+lr, tok = kt*64+ks*32+lg*8 ----
#pragma unroll
    for (int ks = 0; ks < 2; ++ks) {
      bf16x8 pa[2];
#pragma unroll
      for (int it = 0; it < 2; ++it)
        pa[it] = *(const bf16x8*)(pw + (it * 16 + lr) * 72 + ks * 32 + lg * 8);
#pragma unroll
      for (int dt = 0; dt < 4; ++dt) {
        bf16x8 vf = *(const bf16x8*)(Vb + (size_t)(dt * 16 + lr) * 1024 + kt * 64 + ks * 32 + lg * 8);
#pragma unroll
        for (int it = 0; it < 2; ++it)
          acc_o[dt][it] = __builtin_amdgcn_mfma_f32_16x16x32_bf16(vf, pa[it], acc_o[dt][it], 0, 0, 0);
      }
    }
  }

  // ---- denominator: sum over lg-groups (lanes lr, lr+16, lr+32, lr+48), invert ----
  float rinv[2];
#pragma unroll
  for (int it = 0; it < 2; ++it) {
    float v = dsum[it];
    v += __shfl_xor(v, 16);
    v += __shfl_xor(v, 32);
    rinv[it] = __builtin_amdgcn_rcpf(v);
  }

  // ---- write O: token n = qb*128+wv*32+it*16+lr ; feature = h*64 + dt*16 + lg*4 + r ----
#pragma unroll
  for (int dt = 0; dt < 4; ++dt) {
#pragma unroll
    for (int it = 0; it < 2; ++it) {
      float v0 = acc_o[dt][it][0] * rinv[it];
      float v1 = acc_o[dt][it][1] * rinv[it];
      float v2 = acc_o[dt][it][2] * rinv[it];
      float v3 = acc_o[dt][it][3] * rinv[it];
      uint2 w;
      w.x = (uint32_t)f2bf(v0) | ((uint32_t)f2bf(v1) << 16);
      w.y = (uint32_t)f2bf(v2) | ((uint32_t)f2bf(v3) << 16);
      int n = qb * 128 + wv * 32 + it * 16 + lr;
      *(uint2*)(attn + ((size_t)(b * 1024 + n)) * 768 + h * 64 + dt * 16 + lg * 4) = w;
    }
  }
}

// ---------------- GEMM2: output projection (fp32 out) ----------------
__global__ __launch_bounds__(256) void k_gemm_proj(
    const u16* __restrict__ Ain, const u16* __restrict__ Bw, const float* __restrict__ bias,
    float* __restrict__ out) {
  __shared__ u16 As[128 * 32];
  __shared__ u16 Bs[128 * 32];
  int bid = blockIdx.x;
  int wg  = (bid & 7) * 48 + (bid >> 3);
  int bx  = wg % 6, by = wg / 6;

  f32x4 acc[4][4];
#pragma unroll
  for (int mi = 0; mi < 4; ++mi)
#pragma unroll
    for (int ni = 0; ni < 4; ++ni) acc[mi][ni] = (f32x4){0.f, 0.f, 0.f, 0.f};

  gemm_core(Ain, Bw, As, Bs, by * 128, bx * 128, acc);

  const int t = threadIdx.x, lane = t & 63, wv = t >> 6;
  const int wr = wv >> 1, wc = wv & 1, lr = lane & 15, lg = lane >> 4;
  const int col0 = bx * 128 + wc * 64;

  float bv[4];
#pragma unroll
  for (int ni = 0; ni < 4; ++ni) bv[ni] = bias[col0 + ni * 16 + lr];

#pragma unroll
  for (int mi = 0; mi < 4; ++mi) {
    int tok0 = by * 128 + wr * 64 + mi * 16 + lg * 4;
#pragma unroll
    for (int ni = 0; ni < 4; ++ni) {
      int col = col0 + ni * 16 + lr;
#pragma unroll
      for (int r = 0; r < 4; ++r) {
        out[(size_t)(tok0 + r) * 768 + col] = acc[mi][ni][r] + bv[ni];
      }
    }
  }
}

// ---------------- launch ----------------
extern "C" void kernel_launch(void* const* d_in, const int* in_sizes, int n_in,
                              void* d_out, int out_size, void* d_ws, size_t ws_size,
                              hipStream_t stream) {
  (void)in_sizes; (void)n_in; (void)out_size;
  const float* x      = (const float*)d_in[0];
  const float* qkv_w  = (const float*)d_in[1];
  const float* qkv_b  = (const float*)d_in[2];
  const float* proj_w = (const float*)d_in[3];
  const float* proj_b = (const float*)d_in[4];
  float* out = (float*)d_out;

  uint8_t* ws = (uint8_t*)d_ws;
  u16* xb  = (u16*)(ws + 0);          // 8192*768  bf16 (reused as attn_out)
  u16* wqb = (u16*)(ws + 12582912);
  u16* wpb = (u16*)(ws + 16121856);
  u16* Qh  = (u16*)(ws + 17301504);
  u16* Kh  = (u16*)(ws + 42467328);
  u16* Vp  = (u16*)(ws + 67633152);
  u16* Vt  = (u16*)(ws + 80216064);
  if (ws_size < 92798976) return;

  u16* attnb = xb;

  k_convert<<<1024, 256, 0, stream>>>(x, qkv_w, proj_w, xb, wqb, wpb);
  k_gemm_qkv<<<1152, 256, 0, stream>>>(xb, wqb, qkv_b, Qh, Kh, Vp);
  k_transpose_v<<<1536, 256, 0, stream>>>(Vp, Vt);
  k_attn<<<768, 256, 0, stream>>>(Qh, Kh, Vt, attnb);
  k_gemm_proj<<<384, 256, 0, stream>>>(attnb, wpb, proj_b, out);
}

// Round 6
// 164.926 us; speedup vs baseline: 1.3902x; 1.3902x over previous
//
#include <hip/hip_runtime.h>
#include <hip/hip_bf16.h>
#include <stdint.h>

typedef unsigned short u16;
typedef __attribute__((ext_vector_type(8))) short bf16x8;
typedef __attribute__((ext_vector_type(4))) float f32x4;

#define LDS_AS(p) ((__attribute__((address_space(3))) void*)(p))
#define GLB_AS(p) ((__attribute__((address_space(1))) void*)(p))

__device__ __forceinline__ u16 f2bf(float f) {
  union { float f; uint32_t u; } v; v.f = f;
  uint32_t u = v.u;
  u += 0x7fffu + ((u >> 16) & 1u);
  return (u16)(u >> 16);
}

// ---------------- fp32 -> bf16 conversion ----------------
__device__ __forceinline__ void cvt8(const float* __restrict__ s, u16* __restrict__ d) {
  const float4* sv = (const float4*)s;
  float4 a = sv[0], b = sv[1];
  uint4 o;
  o.x = (uint32_t)f2bf(a.x) | ((uint32_t)f2bf(a.y) << 16);
  o.y = (uint32_t)f2bf(a.z) | ((uint32_t)f2bf(a.w) << 16);
  o.z = (uint32_t)f2bf(b.x) | ((uint32_t)f2bf(b.y) << 16);
  o.w = (uint32_t)f2bf(b.z) | ((uint32_t)f2bf(b.w) << 16);
  *(uint4*)d = o;
}

__global__ __launch_bounds__(256) void k_convert(
    const float* __restrict__ x, const float* __restrict__ wq, const float* __restrict__ wp,
    u16* __restrict__ xb, u16* __restrict__ wqb, u16* __restrict__ wpb) {
  int tid = blockIdx.x * 256 + threadIdx.x;
  int np  = gridDim.x * 256;
  for (int i = tid; i < (8192*768)/8; i += np) cvt8(x  + (size_t)i*8, xb  + (size_t)i*8);
  for (int i = tid; i < (2304*768)/8; i += np) cvt8(wq + (size_t)i*8, wqb + (size_t)i*8);
  for (int i = tid; i < (768*768)/8;  i += np) cvt8(wp + (size_t)i*8, wpb + (size_t)i*8);
}

// ---------------- shared 128x128 bf16 GEMM mainloop (A[M,768] . B[N,768]^T) ----------------
__device__ __forceinline__ void gemm_core(const u16* __restrict__ A,
                                          const u16* __restrict__ B,
                                          u16* As, u16* Bs,
                                          int rowA0, int rowB0,
                                          f32x4 acc[4][4]) {
  const int t  = threadIdx.x;
  const int lane = t & 63;
  const int wv = t >> 6;
  const int wr = wv >> 1, wc = wv & 1;
  const int lr = lane & 15, lg = lane >> 4;

#pragma unroll 1
  for (int kt = 0; kt < 24; ++kt) {
    const int k0 = kt * 32;
    __syncthreads();
#pragma unroll
    for (int p = 0; p < 2; ++p) {
      int idx = p * 256 + t;
      int row = idx >> 2;
      int cc  = (idx & 3) ^ ((row >> 1) & 3);
      __builtin_amdgcn_global_load_lds(GLB_AS(A + (size_t)(rowA0 + row) * 768 + k0 + cc * 8),
                                       LDS_AS(As + idx * 8), 16, 0, 0);
    }
#pragma unroll
    for (int p = 0; p < 2; ++p) {
      int idx = p * 256 + t;
      int row = idx >> 2;
      int cc  = (idx & 3) ^ ((row >> 1) & 3);
      __builtin_amdgcn_global_load_lds(GLB_AS(B + (size_t)(rowB0 + row) * 768 + k0 + cc * 8),
                                       LDS_AS(Bs + idx * 8), 16, 0, 0);
    }
    asm volatile("s_waitcnt vmcnt(0)" ::: "memory");
    __syncthreads();

    bf16x8 af[4], bf_[4];
#pragma unroll
    for (int mi = 0; mi < 4; ++mi) {
      int row = wr * 64 + mi * 16 + lr;
      int cc  = lg ^ ((row >> 1) & 3);
      af[mi] = *(const bf16x8*)(As + row * 32 + cc * 8);
    }
#pragma unroll
    for (int ni = 0; ni < 4; ++ni) {
      int row = wc * 64 + ni * 16 + lr;
      int cc  = lg ^ ((row >> 1) & 3);
      bf_[ni] = *(const bf16x8*)(Bs + row * 32 + cc * 8);
    }
#pragma unroll
    for (int mi = 0; mi < 4; ++mi)
#pragma unroll
      for (int ni = 0; ni < 4; ++ni)
        acc[mi][ni] = __builtin_amdgcn_mfma_f32_16x16x32_bf16(af[mi], bf_[ni], acc[mi][ni], 0, 0, 0);
  }
}

// ---------------- GEMM1: qkv projection + scatter into Qhat/Khat/V ----------------
__global__ __launch_bounds__(256) void k_gemm_qkv(
    const u16* __restrict__ Aq, const u16* __restrict__ Bw, const float* __restrict__ bias,
    u16* __restrict__ Qh, u16* __restrict__ Kh, u16* __restrict__ Vp) {
  __shared__ u16 As[128 * 32];
  __shared__ u16 Bs[128 * 32];
  int bid = blockIdx.x;
  int wg  = (bid & 7) * 144 + (bid >> 3);
  int bx  = wg % 18, by = wg / 18;

  f32x4 acc[4][4];
#pragma unroll
  for (int mi = 0; mi < 4; ++mi)
#pragma unroll
    for (int ni = 0; ni < 4; ++ni) acc[mi][ni] = (f32x4){0.f, 0.f, 0.f, 0.f};

  gemm_core(Aq, Bw, As, Bs, by * 128, bx * 128, acc);

  const float gam = 0.7905694150420949f;
  const float sc1 = __builtin_sqrtf(0.09375f / gam);
  const float sc2 = __builtin_sqrtf(0.03125f / gam);

  const int t = threadIdx.x, lane = t & 63, wv = t >> 6;
  const int wr = wv >> 1, wc = wv & 1, lr = lane & 15, lg = lane >> 4;
  const int colBase = bx * 128 + wc * 64;
  const int tsec = (bx * 128) / 768;

  float bv[4];
#pragma unroll
  for (int ni = 0; ni < 4; ++ni) bv[ni] = bias[colBase + ni * 16 + lr];

#pragma unroll
  for (int mi = 0; mi < 4; ++mi) {
    int tok0 = by * 128 + wr * 64 + mi * 16 + lg * 4;
#pragma unroll
    for (int ni = 0; ni < 4; ++ni) {
      int colsec = colBase - tsec * 768 + ni * 16 + lr;
      int h = colsec >> 6, d = colsec & 63;
#pragma unroll
      for (int r = 0; r < 4; ++r) {
        int tok = tok0 + r;
        int b = tok >> 10, n = tok & 1023;
        float val = acc[mi][ni][r] + bv[ni];
        size_t rowq = (size_t)(b * 12 + h) * 1024 + n;
        if (tsec == 0) {
          Qh[rowq * 128 + d]      = f2bf(val * sc1);
          Kh[rowq * 128 + 64 + d] = f2bf(val * sc2);
        } else if (tsec == 1) {
          Qh[rowq * 128 + 64 + d] = f2bf(val * sc2);
          Kh[rowq * 128 + d]      = f2bf(val * sc1);
        } else {
          Vp[rowq * 64 + d] = f2bf(val);
        }
      }
    }
  }
}

// ---------------- V transpose: Vp[bh][n][d] -> Vt[bh][d][n] ----------------
__global__ __launch_bounds__(256) void k_transpose_v(const u16* __restrict__ Vp, u16* __restrict__ Vt) {
  __shared__ u16 tile[64 * 72];
  int bid = blockIdx.x;
  int bh = bid >> 4, nb = bid & 15;
  int t = threadIdx.x;
  {
    int r = t >> 2, c0 = (t & 3) * 16;
    const u16* src = Vp + ((size_t)bh * 1024 + nb * 64 + r) * 64 + c0;
    uint4 a = *(const uint4*)src;
    uint4 b = *(const uint4*)(src + 8);
    *(uint4*)(tile + r * 72 + c0)     = a;
    *(uint4*)(tile + r * 72 + c0 + 8) = b;
  }
  __syncthreads();
  {
    int d = t >> 2, n0 = (t & 3) * 16;
    union { uint4 v; u16 s[8]; } p0, p1;
#pragma unroll
    for (int j = 0; j < 8; ++j) p0.s[j] = tile[(n0 + j) * 72 + d];
#pragma unroll
    for (int j = 0; j < 8; ++j) p1.s[j] = tile[(n0 + 8 + j) * 72 + d];
    u16* dst = Vt + ((size_t)bh * 64 + d) * 1024 + nb * 64 + n0;
    *(uint4*)dst       = p0.v;
    *(uint4*)(dst + 8) = p1.v;
  }
}

// ---------------- fused flash attention: R3 datapath, single K buffer, 3 blocks/CU ----------------
// S^T = Khat . Qhat^T ; p = exp(-10/(e^{0.4 s}+1)) ; O^T = V^T . P ; O /= sum_j p
// Staged K/V via global_load_lds, __syncthreads() barriers, per-wave P LDS round-trip (fenced).
__global__ __launch_bounds__(256, 3) void k_attn(
    const u16* __restrict__ Qh, const u16* __restrict__ Kh, const u16* __restrict__ Vt,
    u16* __restrict__ attn) {
  __shared__ u16 Ks[64 * 128];      // K-tile [64 tok][128 feat], 16B-chunk XOR swizzle
  __shared__ u16 Vs[64 * 64];       // Vt-tile [64 d][64 tok], swizzled
  __shared__ u16 Ps[4][32 * 72];    // per-wave P [32 i][64 j], stride 72 u16 (rows 16B-aligned)

  int bid = blockIdx.x;
  int wg = (bid & 7) * 96 + (bid >> 3);   // 768 = 8*96; a head's 8 q-blocks stay on one XCD
  int bh = wg >> 3, qb = wg & 7;          // 8 q-blocks of 128 rows
  int b = bh / 12, h = bh % 12;

  const int t = threadIdx.x, lane = t & 63, wv = t >> 6;
  const int lr = lane & 15, lg = lane >> 4;

  const size_t khb = (size_t)bh * 1024 * 128;
  const size_t vtb = (size_t)bh * 64 * 1024;

  // Q fragments: qf[it][kk] = Qhat[token = qb*128 + wv*32 + it*16 + lr][k = kk*32 + lg*8 ..+8]
  bf16x8 qf[2][4];
  {
    const u16* qp = Qh + ((size_t)bh * 1024 + qb * 128 + wv * 32 + lr) * 128 + lg * 8;
#pragma unroll
    for (int it = 0; it < 2; ++it)
#pragma unroll
      for (int kk = 0; kk < 4; ++kk)
        qf[it][kk] = *(const bf16x8*)(qp + it * 16 * 128 + kk * 32);
  }

  f32x4 acc_o[4][2];
#pragma unroll
  for (int dt = 0; dt < 4; ++dt)
#pragma unroll
    for (int it = 0; it < 2; ++it) acc_o[dt][it] = (f32x4){0.f, 0.f, 0.f, 0.f};
  float dsum[2] = {0.f, 0.f};

  u16* pw = Ps[wv];

#pragma unroll 1
  for (int kt = 0; kt < 16; ++kt) {
    __syncthreads();   // everyone done reading Ks/Vs of prev iter

    // stage K(kt) (4 loads) + V(kt) (2 loads)
#pragma unroll
    for (int p = 0; p < 4; ++p) {
      int idx = p * 256 + t;
      int row = idx >> 4;
      int cc  = (idx & 15) ^ (row & 7);
      __builtin_amdgcn_global_load_lds(GLB_AS(Kh + khb + (size_t)(kt * 64 + row) * 128 + cc * 8),
                                       LDS_AS(Ks + idx * 8), 16, 0, 0);
    }
#pragma unroll
    for (int p = 0; p < 2; ++p) {
      int idx = p * 256 + t;
      int row = idx >> 3;
      int cc  = (idx & 7) ^ (row & 7);
      __builtin_amdgcn_global_load_lds(GLB_AS(Vt + vtb + (size_t)row * 1024 + kt * 64 + cc * 8),
                                       LDS_AS(Vs + idx * 8), 16, 0, 0);
    }
    __syncthreads();   // compiler drains vmcnt(0): K(kt), V(kt) landed

    // ---- S^T tile: accs[jt][it]; A-frag = Khat row j = jt*16+lr, k-feat = kk*32+lg*8 ----
    f32x4 accs[4][2];
#pragma unroll
    for (int jt = 0; jt < 4; ++jt)
#pragma unroll
      for (int it = 0; it < 2; ++it) accs[jt][it] = (f32x4){0.f, 0.f, 0.f, 0.f};
#pragma unroll
    for (int jt = 0; jt < 4; ++jt) {
#pragma unroll
      for (int kk = 0; kk < 4; ++kk) {
        int row = jt * 16 + lr;
        int cc  = (kk * 4 + lg) ^ (row & 7);
        bf16x8 kf = *(const bf16x8*)(Ks + row * 128 + cc * 8);
#pragma unroll
        for (int it = 0; it < 2; ++it)
          accs[jt][it] = __builtin_amdgcn_mfma_f32_16x16x32_bf16(kf, qf[it][kk], accs[jt][it], 0, 0, 0);
      }
    }

    // ---- p + packed P write: row i = it*16+lr, cols j = jt*16+lg*4..+3 ----
#pragma unroll
    for (int jt = 0; jt < 4; ++jt) {
#pragma unroll
      for (int it = 0; it < 2; ++it) {
        float p0 = __expf(-10.0f * __builtin_amdgcn_rcpf(__expf(0.4f * accs[jt][it][0]) + 1.0f));
        float p1 = __expf(-10.0f * __builtin_amdgcn_rcpf(__expf(0.4f * accs[jt][it][1]) + 1.0f));
        float p2 = __expf(-10.0f * __builtin_amdgcn_rcpf(__expf(0.4f * accs[jt][it][2]) + 1.0f));
        float p3 = __expf(-10.0f * __builtin_amdgcn_rcpf(__expf(0.4f * accs[jt][it][3]) + 1.0f));
        dsum[it] += (p0 + p1) + (p2 + p3);
        uint2 w;
        w.x = (uint32_t)f2bf(p0) | ((uint32_t)f2bf(p1) << 16);
        w.y = (uint32_t)f2bf(p2) | ((uint32_t)f2bf(p3) << 16);
        *(uint2*)(pw + (it * 16 + lr) * 72 + jt * 16 + lg * 4) = w;
      }
    }

    // forbid compiler from reordering the P reads above the P writes (differently-typed LDS access)
    asm volatile("" ::: "memory");

    // ---- O^T += mfma(V-frag, P-frag); same-wave LDS round trip (in-order DS pipe) ----
#pragma unroll
    for (int ks = 0; ks < 2; ++ks) {
      bf16x8 pa[2];
#pragma unroll
      for (int it = 0; it < 2; ++it)
        pa[it] = *(const bf16x8*)(pw + (it * 16 + lr) * 72 + ks * 32 + lg * 8);
#pragma unroll
      for (int dt = 0; dt < 4; ++dt) {
        int row = dt * 16 + lr;
        int cc  = (ks * 4 + lg) ^ (row & 7);
        bf16x8 vf = *(const bf16x8*)(Vs + row * 64 + cc * 8);
#pragma unroll
        for (int it = 0; it < 2; ++it)
          acc_o[dt][it] = __builtin_amdgcn_mfma_f32_16x16x32_bf16(vf, pa[it], acc_o[dt][it], 0, 0, 0);
      }
    }
  }

  // ---- denominator: sum over lg-groups (lanes lr, lr+16, lr+32, lr+48), invert ----
  float rinv[2];
#pragma unroll
  for (int it = 0; it < 2; ++it) {
    float v = dsum[it];
    v += __shfl_xor(v, 16);
    v += __shfl_xor(v, 32);
    rinv[it] = __builtin_amdgcn_rcpf(v);
  }

  // ---- write O: token n = qb*128+wv*32+it*16+lr ; feature = h*64 + dt*16 + lg*4 + r ----
#pragma unroll
  for (int dt = 0; dt < 4; ++dt) {
#pragma unroll
    for (int it = 0; it < 2; ++it) {
      float v0 = acc_o[dt][it][0] * rinv[it];
      float v1 = acc_o[dt][it][1] * rinv[it];
      float v2 = acc_o[dt][it][2] * rinv[it];
      float v3 = acc_o[dt][it][3] * rinv[it];
      uint2 w;
      w.x = (uint32_t)f2bf(v0) | ((uint32_t)f2bf(v1) << 16);
      w.y = (uint32_t)f2bf(v2) | ((uint32_t)f2bf(v3) << 16);
      int n = qb * 128 + wv * 32 + it * 16 + lr;
      *(uint2*)(attn + ((size_t)(b * 1024 + n)) * 768 + h * 64 + dt * 16 + lg * 4) = w;
    }
  }
}

// ---------------- GEMM2: output projection (fp32 out) ----------------
__global__ __launch_bounds__(256) void k_gemm_proj(
    const u16* __restrict__ Ain, const u16* __restrict__ Bw, const float* __restrict__ bias,
    float* __restrict__ out) {
  __shared__ u16 As[128 * 32];
  __shared__ u16 Bs[128 * 32];
  int bid = blockIdx.x;
  int wg  = (bid & 7) * 48 + (bid >> 3);
  int bx  = wg % 6, by = wg / 6;

  f32x4 acc[4][4];
#pragma unroll
  for (int mi = 0; mi < 4; ++mi)
#pragma unroll
    for (int ni = 0; ni < 4; ++ni) acc[mi][ni] = (f32x4){0.f, 0.f, 0.f, 0.f};

  gemm_core(Ain, Bw, As, Bs, by * 128, bx * 128, acc);

  const int t = threadIdx.x, lane = t & 63, wv = t >> 6;
  const int wr = wv >> 1, wc = wv & 1, lr = lane & 15, lg = lane >> 4;
  const int col0 = bx * 128 + wc * 64;

  float bv[4];
#pragma unroll
  for (int ni = 0; ni < 4; ++ni) bv[ni] = bias[col0 + ni * 16 + lr];

#pragma unroll
  for (int mi = 0; mi < 4; ++mi) {
    int tok0 = by * 128 + wr * 64 + mi * 16 + lg * 4;
#pragma unroll
    for (int ni = 0; ni < 4; ++ni) {
      int col = col0 + ni * 16 + lr;
#pragma unroll
      for (int r = 0; r < 4; ++r) {
        out[(size_t)(tok0 + r) * 768 + col] = acc[mi][ni][r] + bv[ni];
      }
    }
  }
}

// ---------------- launch ----------------
extern "C" void kernel_launch(void* const* d_in, const int* in_sizes, int n_in,
                              void* d_out, int out_size, void* d_ws, size_t ws_size,
                              hipStream_t stream) {
  (void)in_sizes; (void)n_in; (void)out_size;
  const float* x      = (const float*)d_in[0];
  const float* qkv_w  = (const float*)d_in[1];
  const float* qkv_b  = (const float*)d_in[2];
  const float* proj_w = (const float*)d_in[3];
  const float* proj_b = (const float*)d_in[4];
  float* out = (float*)d_out;

  uint8_t* ws = (uint8_t*)d_ws;
  u16* xb  = (u16*)(ws + 0);          // 8192*768  bf16 (reused as attn_out)
  u16* wqb = (u16*)(ws + 12582912);
  u16* wpb = (u16*)(ws + 16121856);
  u16* Qh  = (u16*)(ws + 17301504);
  u16* Kh  = (u16*)(ws + 42467328);
  u16* Vp  = (u16*)(ws + 67633152);
  u16* Vt  = (u16*)(ws + 80216064);
  if (ws_size < 92798976) return;

  u16* attnb = xb;

  k_convert<<<1024, 256, 0, stream>>>(x, qkv_w, proj_w, xb, wqb, wpb);
  k_gemm_qkv<<<1152, 256, 0, stream>>>(xb, wqb, qkv_b, Qh, Kh, Vp);
  k_transpose_v<<<1536, 256, 0, stream>>>(Vp, Vt);
  k_attn<<<768, 256, 0, stream>>>(Qh, Kh, Vt, attnb);
  k_gemm_proj<<<384, 256, 0, stream>>>(attnb, wpb, proj_b, out);
}